// Round 10
// baseline (285.183 us; speedup 1.0000x reference)
//
#include <hip/hip_runtime.h>
#include <math.h>

#define N_NODES 50000
#define D 128       // d_in == d_hid
#define D_OUT 64
#define CSRB 512    // csr_kernel blocks (>= co-residency floor of 2/CU x 256 CU)

typedef short bf16x8 __attribute__((ext_vector_type(8)));   // 8 bf16 (4 VGPR) MFMA frag
typedef float f32x4  __attribute__((ext_vector_type(4)));   // MFMA accumulator
typedef unsigned short u16x8 __attribute__((ext_vector_type(8)));

__device__ __forceinline__ unsigned short f_to_bf16(float f) {
    unsigned int u = __float_as_uint(f);
    u = (u + 0x7fffu + ((u >> 16) & 1u)) >> 16;   // RNE
    return (unsigned short)u;
}
__device__ __forceinline__ float bf16lo(unsigned int v) { return __uint_as_float(v << 16); }
__device__ __forceinline__ float bf16hi(unsigned int v) { return __uint_as_float(v & 0xffff0000u); }
__device__ __forceinline__ float bf16f(unsigned short v) { return __uint_as_float((unsigned int)v << 16); }

__device__ __forceinline__ void conv8(const float* __restrict__ src, unsigned short* __restrict__ dst, int i)
{
    float4 v0 = *reinterpret_cast<const float4*>(src + i);
    float4 v1 = *reinterpret_cast<const float4*>(src + i + 4);
    u16x8 o;
    o[0] = f_to_bf16(v0.x); o[1] = f_to_bf16(v0.y);
    o[2] = f_to_bf16(v0.z); o[3] = f_to_bf16(v0.w);
    o[4] = f_to_bf16(v1.x); o[5] = f_to_bf16(v1.y);
    o[6] = f_to_bf16(v1.z); o[7] = f_to_bf16(v1.w);
    *reinterpret_cast<u16x8*>(dst + i) = o;
}

__device__ __forceinline__ void acc_add(float* acc, uint4 v)
{
    acc[0] += bf16lo(v.x); acc[1] += bf16hi(v.x);
    acc[2] += bf16lo(v.y); acc[3] += bf16hi(v.y);
    acc[4] += bf16lo(v.z); acc[5] += bf16hi(v.z);
    acc[6] += bf16lo(v.w); acc[7] += bf16hi(v.w);
}

// ---------------------------------------------------------------------------
// Dispatch 1: conv_x | conv_w | zero(deg,cursor) | zero(barriers)
// ---------------------------------------------------------------------------
__global__ __launch_bounds__(256) void conv_kernel(
    const float* __restrict__ x, unsigned short* __restrict__ xb,
    const float* __restrict__ w1l, const float* __restrict__ w1r,
    const float* __restrict__ w2l, const float* __restrict__ w2r,
    unsigned short* __restrict__ Wb,
    int* __restrict__ degcur, int* __restrict__ bar,
    int XB, int ZB)
{
    const int bx = blockIdx.x;
    if (bx < XB) {
        int i = (bx * 256 + threadIdx.x) * 8;
        if (i < N_NODES * D) conv8(x, xb, i);
    } else if (bx < XB + 24) {
        int i = ((bx - XB) * 256 + threadIdx.x) * 8;   // 49152 elems
        const float* src; int off;
        if      (i < 16384) { src = w1l; off = 0; }
        else if (i < 32768) { src = w1r; off = 16384; }
        else if (i < 40960) { src = w2l; off = 32768; }
        else                { src = w2r; off = 40960; }
        conv8(src, Wb + off, i - off);
    } else if (bx < XB + 24 + ZB) {
        int i = (bx - XB - 24) * 256 + threadIdx.x;    // int4 over 2N ints
        if (i < 2 * N_NODES / 4)
            *reinterpret_cast<int4*>(degcur + i * 4) = make_int4(0, 0, 0, 0);
    } else {
        if (threadIdx.x < 16) bar[threadIdx.x] = 0;
    }
}

// ---------------------------------------------------------------------------
// Device-scope grid barrier (agent scope atomics: cross-XCD coherent).
// Safe because csr_kernel's CSRB blocks are co-resident (launch_bounds(256,2)).
// ---------------------------------------------------------------------------
__device__ __forceinline__ void gbar(int* bar, int idx, int nblk)
{
    __syncthreads();
    if (threadIdx.x == 0) {
        __threadfence();
        __hip_atomic_fetch_add(&bar[idx], 1, __ATOMIC_ACQ_REL, __HIP_MEMORY_SCOPE_AGENT);
        while (__hip_atomic_load(&bar[idx], __ATOMIC_ACQUIRE, __HIP_MEMORY_SCOPE_AGENT) < nblk)
            __builtin_amdgcn_s_sleep(1);
        __threadfence();
    }
    __syncthreads();
}

// ---------------------------------------------------------------------------
// Dispatch 2: whole CSR build. hist -> bar -> local scan -> bar ->
// offsets+row_ptr -> bar -> fill.
// ---------------------------------------------------------------------------
__global__ __launch_bounds__(256, 2) void csr_kernel(
    const int* __restrict__ src, const int* __restrict__ dst,
    int* __restrict__ deg, int* __restrict__ cursor,
    int* __restrict__ row_ptr, int* __restrict__ part,
    int* __restrict__ bsum, int* __restrict__ esrc,
    int* __restrict__ bar, int E)
{
    __shared__ int wsum[4];
    __shared__ int sAdd, sTot;
    const int t = threadIdx.x;
    const int bid = blockIdx.x;

    // ---- phase 1: in-degree histogram ----
    for (int e = bid * 256 + t; e < E; e += CSRB * 256)
        atomicAdd(&deg[dst[e]], 1);
    gbar(bar, 0, CSRB);

    // ---- phase 2: per-block local exclusive scan (blocks 0..48) ----
    if (bid < 49) {
        const int base = bid * 1024 + t * 4;
        int a0 = 0, a1 = 0, a2 = 0, a3 = 0;
        if (base + 3 < N_NODES) {
            int4 v = *reinterpret_cast<const int4*>(deg + base);
            a0 = v.x; a1 = v.y; a2 = v.z; a3 = v.w;
        } else if (base < N_NODES) {
            a0 = deg[base];
            if (base + 1 < N_NODES) a1 = deg[base + 1];
            if (base + 2 < N_NODES) a2 = deg[base + 2];
        }
        const int s0 = a0, s1 = s0 + a1, s2 = s1 + a2, s3 = s2 + a3;

        const int lane = t & 63;
        int incl = s3;
#pragma unroll
        for (int off = 1; off < 64; off <<= 1) {
            int up = __shfl_up(incl, off);
            if (lane >= off) incl += up;
        }
        const int wid = t >> 6;
        if (lane == 63) wsum[wid] = incl;
        __syncthreads();
        int woff = 0;
#pragma unroll
        for (int w = 0; w < 4; ++w) woff += (w < wid) ? wsum[w] : 0;

        const int ex = woff + incl - s3;
        if (base + 3 < N_NODES) {
            int4 o; o.x = ex; o.y = ex + s0; o.z = ex + s1; o.w = ex + s2;
            *reinterpret_cast<int4*>(part + base) = o;
        } else if (base < N_NODES) {
            part[base] = ex;
            if (base + 1 < N_NODES) part[base + 1] = ex + s0;
            if (base + 2 < N_NODES) part[base + 2] = ex + s1;
        }
        if (t == 255) bsum[bid] = woff + incl;
    }
    gbar(bar, 1, CSRB);

    // ---- phase 3: add block offsets -> row_ptr ----
    if (bid < 49) {
        if (t < 64) {
            int v   = (t < 49) ? bsum[t] : 0;
            int pre = (t < bid) ? v : 0;
            int add = pre, tot = v;
#pragma unroll
            for (int off = 1; off < 64; off <<= 1) {
                add += __shfl_xor(add, off);
                tot += __shfl_xor(tot, off);
            }
            if (t == 0) { sAdd = add; sTot = tot; }
        }
        __syncthreads();
        const int add = sAdd;
        const int base = bid * 1024 + t * 4;
        if (base + 3 < N_NODES) {
            int4 v = *reinterpret_cast<const int4*>(part + base);
            v.x += add; v.y += add; v.z += add; v.w += add;
            *reinterpret_cast<int4*>(row_ptr + base) = v;
        } else if (base < N_NODES) {
            row_ptr[base] = part[base] + add;
            if (base + 1 < N_NODES) row_ptr[base + 1] = part[base + 1] + add;
            if (base + 2 < N_NODES) row_ptr[base + 2] = part[base + 2] + add;
        }
        if (bid == 48 && t == 0) row_ptr[N_NODES] = sTot;
    }
    gbar(bar, 2, CSRB);

    // ---- phase 4: bucket-fill ----
    for (int e = bid * 256 + t; e < E; e += CSRB * 256) {
        int d = dst[e];
        int pos = atomicAdd(&cursor[d], 1);
        esrc[row_ptr[d] + pos] = src[e];
    }
}

// ---------------------------------------------------------------------------
// Dispatch 3: gather(x) into LDS + layer1 MFMA + t2 = h1·W2l^T.
// Block = 16 nodes (one MFMA tile), 4 waves; wave gathers 4 nodes (256B rows,
// 4 rows/load, 16 in flight), then computes 2 of 8 jt slices + 1 t2 slice.
// D-layout: col = lane&15, row = (lane>>4)*4 + reg   [m89 verified]
// ---------------------------------------------------------------------------
__global__ __launch_bounds__(256) void gather_layer1_kernel(
    const unsigned short* __restrict__ xb,
    const int* __restrict__ row_ptr, const int* __restrict__ esrc,
    const unsigned short* __restrict__ Wb,   // W1l@0, W1r@16384, W2l@32768
    const float* __restrict__ b1,
    unsigned short* __restrict__ h1b, unsigned short* __restrict__ t2b)
{
    __shared__ unsigned short aggs[16][136];   // 272B rows: 16B-aligned, 2-way alias
    __shared__ unsigned short h1s[16][136];

    const int t = threadIdx.x;
    const int wv = t >> 6, lane = t & 63;
    const int node0 = blockIdx.x * 16;
    const int g = lane >> 4, c = lane & 15;
    const uint4* x4 = reinterpret_cast<const uint4*>(xb);

    for (int i4 = 0; i4 < 4; ++i4) {
        const int ln = wv * 4 + i4;
        const int node = node0 + ln;
        const int beg = row_ptr[node], end = row_ptr[node + 1];

        float acc[8];
#pragma unroll
        for (int k = 0; k < 8; ++k) acc[k] = 0.f;

        for (int base = beg; base < end; base += 64) {
            const int cnt = min(end - base, 64);
            int s = (base + lane < end) ? esrc[base + lane] : 0;
            for (int i = 0; i < cnt; i += 16) {
                int pp[4]; uint4 vv[4];
#pragma unroll
                for (int j = 0; j < 4; ++j) {
                    pp[j] = i + j * 4 + g;
                    int sj = __shfl(s, pp[j]);
                    vv[j] = x4[(size_t)sj * 16 + c];
                }
#pragma unroll
                for (int j = 0; j < 4; ++j)
                    if (pp[j] < cnt) acc_add(acc, vv[j]);
            }
        }
#pragma unroll
        for (int k = 0; k < 8; ++k) {
            acc[k] += __shfl_xor(acc[k], 16);
            acc[k] += __shfl_xor(acc[k], 32);
        }
        if (g == 0) {
            const float inv = (end > beg) ? 1.0f / (float)(end - beg) : 0.0f;
            uint4 o;
            o.x = (unsigned int)f_to_bf16(acc[0] * inv) | ((unsigned int)f_to_bf16(acc[1] * inv) << 16);
            o.y = (unsigned int)f_to_bf16(acc[2] * inv) | ((unsigned int)f_to_bf16(acc[3] * inv) << 16);
            o.z = (unsigned int)f_to_bf16(acc[4] * inv) | ((unsigned int)f_to_bf16(acc[5] * inv) << 16);
            o.w = (unsigned int)f_to_bf16(acc[6] * inv) | ((unsigned int)f_to_bf16(acc[7] * inv) << 16);
            *reinterpret_cast<uint4*>(&aggs[ln][c * 8]) = o;
        }
    }
    __syncthreads();

    const int c16 = lane & 15, kg = lane >> 4;
    bf16x8 aL[4], aR[4];
#pragma unroll
    for (int kf = 0; kf < 4; ++kf) {
        aL[kf] = *reinterpret_cast<const bf16x8*>(&aggs[c16][kg * 8 + kf * 32]);
        aR[kf] = *reinterpret_cast<const bf16x8*>(xb + (size_t)(node0 + c16) * D + kg * 8 + kf * 32);
    }

#pragma unroll
    for (int jj = 0; jj < 2; ++jj) {
        const int jt = wv + jj * 4;
        f32x4 acc = {0.f, 0.f, 0.f, 0.f};
        const unsigned short* wl = Wb +         (size_t)(jt * 16 + c16) * D + kg * 8;
        const unsigned short* wr = Wb + 16384 + (size_t)(jt * 16 + c16) * D + kg * 8;
#pragma unroll
        for (int kf = 0; kf < 4; ++kf) {
            bf16x8 b = *reinterpret_cast<const bf16x8*>(wl + kf * 32);
            acc = __builtin_amdgcn_mfma_f32_16x16x32_bf16(aL[kf], b, acc, 0, 0, 0);
        }
#pragma unroll
        for (int kf = 0; kf < 4; ++kf) {
            bf16x8 b = *reinterpret_cast<const bf16x8*>(wr + kf * 32);
            acc = __builtin_amdgcn_mfma_f32_16x16x32_bf16(aR[kf], b, acc, 0, 0, 0);
        }
        const float bias = b1[jt * 16 + c16];
#pragma unroll
        for (int i = 0; i < 4; ++i) {
            float v = fmaxf(acc[i] + bias, 0.0f);
            unsigned short us = f_to_bf16(v);
            h1b[(size_t)(node0 + kg * 4 + i) * D + jt * 16 + c16] = us;
            h1s[kg * 4 + i][jt * 16 + c16] = us;
        }
    }
    __syncthreads();

    {   // t2 slice: jt = wv (0..3)
        const int jt = wv;
        bf16x8 a2[4];
#pragma unroll
        for (int kf = 0; kf < 4; ++kf)
            a2[kf] = *reinterpret_cast<const bf16x8*>(&h1s[c16][kg * 8 + kf * 32]);
        f32x4 acc = {0.f, 0.f, 0.f, 0.f};
        const unsigned short* wl = Wb + 32768 + (size_t)(jt * 16 + c16) * D + kg * 8;
#pragma unroll
        for (int kf = 0; kf < 4; ++kf) {
            bf16x8 b = *reinterpret_cast<const bf16x8*>(wl + kf * 32);
            acc = __builtin_amdgcn_mfma_f32_16x16x32_bf16(a2[kf], b, acc, 0, 0, 0);
        }
#pragma unroll
        for (int i = 0; i < 4; ++i)
            t2b[(size_t)(node0 + kg * 4 + i) * D_OUT + jt * 16 + c16] = f_to_bf16(acc[i]);
    }
}

// ---------------------------------------------------------------------------
// Dispatch 4: gather(t2, 128B rows) into LDS + layer2 right GEMM + log_softmax.
// ---------------------------------------------------------------------------
__global__ __launch_bounds__(256) void gather_layer2_kernel(
    const unsigned short* __restrict__ t2b,
    const unsigned short* __restrict__ h1b,
    const int* __restrict__ row_ptr, const int* __restrict__ esrc,
    const unsigned short* __restrict__ Wb,   // W2r@40960
    const float* __restrict__ b2, float* __restrict__ out)
{
    __shared__ unsigned short agg2s[16][72];   // 144B rows
    __shared__ float zs[16][68];               // 272B rows

    const int t = threadIdx.x;
    const int wv = t >> 6, lane = t & 63;
    const int node0 = blockIdx.x * 16;
    const int g = lane >> 3, c = lane & 7;     // 8 row slots x 8 chunks
    const uint4* t4 = reinterpret_cast<const uint4*>(t2b);

    for (int i4 = 0; i4 < 4; ++i4) {
        const int ln = wv * 4 + i4;
        const int node = node0 + ln;
        const int beg = row_ptr[node], end = row_ptr[node + 1];

        float acc[8];
#pragma unroll
        for (int k = 0; k < 8; ++k) acc[k] = 0.f;

        for (int base = beg; base < end; base += 64) {
            const int cnt = min(end - base, 64);
            int s = (base + lane < end) ? esrc[base + lane] : 0;
            for (int i = 0; i < cnt; i += 16) {
                int pp[2]; uint4 vv[2];
#pragma unroll
                for (int j = 0; j < 2; ++j) {
                    pp[j] = i + j * 8 + g;
                    int sj = __shfl(s, pp[j]);
                    vv[j] = t4[(size_t)sj * 8 + c];
                }
#pragma unroll
                for (int j = 0; j < 2; ++j)
                    if (pp[j] < cnt) acc_add(acc, vv[j]);
            }
        }
#pragma unroll
        for (int k = 0; k < 8; ++k) {
            acc[k] += __shfl_xor(acc[k], 8);
            acc[k] += __shfl_xor(acc[k], 16);
            acc[k] += __shfl_xor(acc[k], 32);
        }
        if (g == 0) {
            const float inv = (end > beg) ? 1.0f / (float)(end - beg) : 0.0f;
            uint4 o;
            o.x = (unsigned int)f_to_bf16(acc[0] * inv) | ((unsigned int)f_to_bf16(acc[1] * inv) << 16);
            o.y = (unsigned int)f_to_bf16(acc[2] * inv) | ((unsigned int)f_to_bf16(acc[3] * inv) << 16);
            o.z = (unsigned int)f_to_bf16(acc[4] * inv) | ((unsigned int)f_to_bf16(acc[5] * inv) << 16);
            o.w = (unsigned int)f_to_bf16(acc[6] * inv) | ((unsigned int)f_to_bf16(acc[7] * inv) << 16);
            *reinterpret_cast<uint4*>(&agg2s[ln][c * 8]) = o;
        }
    }
    __syncthreads();

    {   // right GEMM slice jt = wv; z staged to LDS
        const int c16 = lane & 15, kg = lane >> 4;
        const int jt = wv;
        bf16x8 a[4];
#pragma unroll
        for (int kf = 0; kf < 4; ++kf)
            a[kf] = *reinterpret_cast<const bf16x8*>(h1b + (size_t)(node0 + c16) * D + kg * 8 + kf * 32);
        f32x4 acc = {0.f, 0.f, 0.f, 0.f};
        const unsigned short* wr = Wb + 40960 + (size_t)(jt * 16 + c16) * D + kg * 8;
#pragma unroll
        for (int kf = 0; kf < 4; ++kf) {
            bf16x8 b = *reinterpret_cast<const bf16x8*>(wr + kf * 32);
            acc = __builtin_amdgcn_mfma_f32_16x16x32_bf16(a[kf], b, acc, 0, 0, 0);
        }
        const float bias = b2[jt * 16 + c16];
#pragma unroll
        for (int i = 0; i < 4; ++i) {
            const int row = kg * 4 + i;
            float left = bf16f(agg2s[row][jt * 16 + c16]);
            zs[row][jt * 16 + c16] = left + acc[i] + bias;
        }
    }
    __syncthreads();

    // softmax: wave wv handles 4 rows; 64-lane reduce
    for (int i4 = 0; i4 < 4; ++i4) {
        const int ln = wv * 4 + i4;
        float z = zs[ln][lane];
        float m = z;
#pragma unroll
        for (int off = 1; off < 64; off <<= 1)
            m = fmaxf(m, __shfl_xor(m, off));
        float e = expf(z - m);
        float s = e;
#pragma unroll
        for (int off = 1; off < 64; off <<= 1)
            s += __shfl_xor(s, off);
        out[(size_t)(node0 + ln) * D_OUT + lane] = z - m - logf(s);
    }
}

// ---------------------------------------------------------------------------
extern "C" void kernel_launch(void* const* d_in, const int* in_sizes, int n_in,
                              void* d_out, int out_size, void* d_ws, size_t ws_size,
                              hipStream_t stream)
{
    const float* x   = (const float*)d_in[0];
    const int*   ei  = (const int*)d_in[1];
    const float* W1l = (const float*)d_in[2];
    const float* b1  = (const float*)d_in[3];
    const float* W1r = (const float*)d_in[4];
    const float* W2l = (const float*)d_in[5];
    const float* b2  = (const float*)d_in[6];
    const float* W2r = (const float*)d_in[7];
    float* out = (float*)d_out;

    const int E = in_sizes[1] / 2;
    const int* src = ei;
    const int* dst = ei + E;

    // ---- workspace layout (256B-aligned chunks) ----
    char* base = (char*)d_ws;
    size_t off = 0;
    auto take = [&](size_t bytes) { char* p = base + off; off += (bytes + 255) & ~(size_t)255; return p; };

    unsigned short* xb  = (unsigned short*)take((size_t)N_NODES * D * 2);
    unsigned short* h1b = (unsigned short*)take((size_t)N_NODES * D * 2);
    unsigned short* t2b = (unsigned short*)take((size_t)N_NODES * D_OUT * 2);
    unsigned short* Wb  = (unsigned short*)take((size_t)49152 * 2);
    int* degcur  = (int*)take((size_t)2 * N_NODES * 4);   // deg | cursor
    int* deg     = degcur;
    int* cursor  = degcur + N_NODES;
    int* row_ptr = (int*)take(((size_t)N_NODES + 1) * 4);
    int* part    = (int*)take((size_t)N_NODES * 4);
    int* bsum    = (int*)take((size_t)64 * 4);
    int* esrc    = (int*)take((size_t)E * 4);
    int* bar     = (int*)take((size_t)16 * 4);

    const int XB = (N_NODES * D / 8 + 255) / 256;        // 3125 conv_x blocks
    const int ZB = (2 * N_NODES / 4 + 255) / 256;        // 98 zero blocks
    const int MB = N_NODES / 16;                         // 3125 tile blocks, exact

    // 1) conversions + zeroing + barrier init
    conv_kernel<<<XB + 24 + ZB + 1, 256, 0, stream>>>(
        x, xb, W1l, W1r, W2l, W2r, Wb, degcur, bar, XB, ZB);
    // 2) full CSR build (hist/scan/fill with internal device barriers)
    csr_kernel<<<CSRB, 256, 0, stream>>>(
        src, dst, deg, cursor, row_ptr, part, bsum, esrc, bar, E);
    // 3) gather(x) + layer1 + t2
    gather_layer1_kernel<<<MB, 256, 0, stream>>>(
        xb, row_ptr, esrc, Wb, b1, h1b, t2b);
    // 4) gather(t2) + layer2 + log_softmax
    gather_layer2_kernel<<<MB, 256, 0, stream>>>(
        t2b, h1b, row_ptr, esrc, Wb, b2, out);
}

// Round 11
// 169.181 us; speedup vs baseline: 1.6857x; 1.6857x over previous
//
#include <hip/hip_runtime.h>
#include <math.h>

#define N_NODES 50000
#define D 128       // d_in == d_hid
#define D_OUT 64

typedef short bf16x8 __attribute__((ext_vector_type(8)));   // 8 bf16 (4 VGPR) MFMA frag
typedef float f32x4  __attribute__((ext_vector_type(4)));   // MFMA accumulator
typedef unsigned short u16x8 __attribute__((ext_vector_type(8)));

__device__ __forceinline__ unsigned short f_to_bf16(float f) {
    unsigned int u = __float_as_uint(f);
    u = (u + 0x7fffu + ((u >> 16) & 1u)) >> 16;   // RNE
    return (unsigned short)u;
}
__device__ __forceinline__ float bf16lo(unsigned int v) { return __uint_as_float(v << 16); }
__device__ __forceinline__ float bf16hi(unsigned int v) { return __uint_as_float(v & 0xffff0000u); }
__device__ __forceinline__ float bf16f(unsigned short v) { return __uint_as_float((unsigned int)v << 16); }

__device__ __forceinline__ void conv8(const float* __restrict__ src, unsigned short* __restrict__ dst, int i)
{
    float4 v0 = *reinterpret_cast<const float4*>(src + i);
    float4 v1 = *reinterpret_cast<const float4*>(src + i + 4);
    u16x8 o;
    o[0] = f_to_bf16(v0.x); o[1] = f_to_bf16(v0.y);
    o[2] = f_to_bf16(v0.z); o[3] = f_to_bf16(v0.w);
    o[4] = f_to_bf16(v1.x); o[5] = f_to_bf16(v1.y);
    o[6] = f_to_bf16(v1.z); o[7] = f_to_bf16(v1.w);
    *reinterpret_cast<u16x8*>(dst + i) = o;
}

__device__ __forceinline__ void acc_add(float* acc, uint4 v)
{
    acc[0] += bf16lo(v.x); acc[1] += bf16hi(v.x);
    acc[2] += bf16lo(v.y); acc[3] += bf16hi(v.y);
    acc[4] += bf16lo(v.z); acc[5] += bf16hi(v.z);
    acc[6] += bf16lo(v.w); acc[7] += bf16hi(v.w);
}

// ---------------------------------------------------------------------------
// Zero deg|cursor
// ---------------------------------------------------------------------------
__global__ __launch_bounds__(256) void zero_kernel(int* __restrict__ p, int n4)
{
    int i = blockIdx.x * 256 + threadIdx.x;
    if (i < n4) *reinterpret_cast<int4*>(p + i * 4) = make_int4(0, 0, 0, 0);
}

// ---------------------------------------------------------------------------
// Fused prep: conv_x | conv_w | hist, dispatched by block range.
// ---------------------------------------------------------------------------
__global__ __launch_bounds__(256) void prep_kernel(
    const float* __restrict__ x, unsigned short* __restrict__ xb,
    const float* __restrict__ w1l, const float* __restrict__ w1r,
    const float* __restrict__ w2l, const float* __restrict__ w2r,
    unsigned short* __restrict__ Wb,
    const int* __restrict__ dst, int* __restrict__ deg,
    int XB, int E)
{
    const int bx = blockIdx.x;
    if (bx < XB) {
        int i = (bx * 256 + threadIdx.x) * 8;
        if (i < N_NODES * D) conv8(x, xb, i);
    } else if (bx < XB + 24) {
        int i = ((bx - XB) * 256 + threadIdx.x) * 8;   // 49152 elems
        const float* src; int off;
        if      (i < 16384) { src = w1l; off = 0; }
        else if (i < 32768) { src = w1r; off = 16384; }
        else if (i < 40960) { src = w2l; off = 32768; }
        else                { src = w2r; off = 40960; }
        conv8(src, Wb + off, i - off);
    } else {
        int e = (bx - XB - 24) * 256 + threadIdx.x;
        if (e < E) atomicAdd(&deg[dst[e]], 1);
    }
}

// ---------------------------------------------------------------------------
// Hierarchical exclusive scan (3 tiny dispatches — dispatch gap IS the barrier)
// ---------------------------------------------------------------------------
__global__ __launch_bounds__(256) void scan1_kernel(
    const int* __restrict__ deg, int* __restrict__ part,
    int* __restrict__ bsum, int n)
{
    const int t = threadIdx.x;
    const int base = blockIdx.x * 1024 + t * 4;

    int a0 = 0, a1 = 0, a2 = 0, a3 = 0;
    if (base + 3 < n) {
        int4 v = *reinterpret_cast<const int4*>(deg + base);
        a0 = v.x; a1 = v.y; a2 = v.z; a3 = v.w;
    } else if (base < n) {
        a0 = deg[base];
        if (base + 1 < n) a1 = deg[base + 1];
        if (base + 2 < n) a2 = deg[base + 2];
    }
    const int s0 = a0, s1 = s0 + a1, s2 = s1 + a2, s3 = s2 + a3;

    const int lane = t & 63;
    int incl = s3;
#pragma unroll
    for (int off = 1; off < 64; off <<= 1) {
        int up = __shfl_up(incl, off);
        if (lane >= off) incl += up;
    }

    __shared__ int wsum[4];
    const int wid = t >> 6;
    if (lane == 63) wsum[wid] = incl;
    __syncthreads();

    int woff = 0;
#pragma unroll
    for (int w = 0; w < 4; ++w) woff += (w < wid) ? wsum[w] : 0;

    const int ex = woff + incl - s3;
    if (base + 3 < n) {
        int4 o; o.x = ex; o.y = ex + s0; o.z = ex + s1; o.w = ex + s2;
        *reinterpret_cast<int4*>(part + base) = o;
    } else if (base < n) {
        part[base] = ex;
        if (base + 1 < n) part[base + 1] = ex + s0;
        if (base + 2 < n) part[base + 2] = ex + s1;
    }
    if (t == 255) bsum[blockIdx.x] = woff + incl;
}

__global__ __launch_bounds__(64) void scan2_kernel(
    int* __restrict__ bsum, int* __restrict__ row_ptr, int nb, int n)
{
    const int t = threadIdx.x;
    int v = (t < nb) ? bsum[t] : 0;
    int incl = v;
#pragma unroll
    for (int off = 1; off < 64; off <<= 1) {
        int up = __shfl_up(incl, off);
        if (t >= off) incl += up;
    }
    if (t < nb) bsum[t] = incl - v;
    if (t == 63) row_ptr[n] = incl;
}

__global__ __launch_bounds__(256) void scan3_kernel(
    const int* __restrict__ part, const int* __restrict__ bsum,
    int* __restrict__ row_ptr, int n)
{
    const int base = blockIdx.x * 1024 + threadIdx.x * 4;
    const int add = bsum[blockIdx.x];
    if (base + 3 < n) {
        int4 v = *reinterpret_cast<const int4*>(part + base);
        v.x += add; v.y += add; v.z += add; v.w += add;
        *reinterpret_cast<int4*>(row_ptr + base) = v;
    } else if (base < n) {
        row_ptr[base] = part[base] + add;
        if (base + 1 < n) row_ptr[base + 1] = part[base + 1] + add;
        if (base + 2 < n) row_ptr[base + 2] = part[base + 2] + add;
    }
}

// ---------------------------------------------------------------------------
// CSR bucket-fill
// ---------------------------------------------------------------------------
__global__ __launch_bounds__(256) void fill_kernel(
    const int* __restrict__ src, const int* __restrict__ dst,
    const int* __restrict__ row_ptr, int* __restrict__ cursor,
    int* __restrict__ esrc, int E)
{
    int e = blockIdx.x * blockDim.x + threadIdx.x;
    if (e >= E) return;
    int d = dst[e];
    int pos = atomicAdd(&cursor[d], 1);
    esrc[row_ptr[d] + pos] = src[e];
}

// ---------------------------------------------------------------------------
// Fused gather(x) + layer1 MFMA + t2 = h1·W2l^T.   [validated in round 10]
// Block = 16 nodes, 4 waves; wave gathers 4 nodes (256B rows, 4 rows/load,
// 16 in flight), agg staged in LDS; then 2 jt slices of layer1 + 1 t2 slice.
// D-layout: col = lane&15, row = (lane>>4)*4 + reg   [m89 verified]
// ---------------------------------------------------------------------------
__global__ __launch_bounds__(256) void gather_layer1_kernel(
    const unsigned short* __restrict__ xb,
    const int* __restrict__ row_ptr, const int* __restrict__ esrc,
    const unsigned short* __restrict__ Wb,   // W1l@0, W1r@16384, W2l@32768
    const float* __restrict__ b1,
    unsigned short* __restrict__ h1b, unsigned short* __restrict__ t2b)
{
    __shared__ unsigned short aggs[16][136];   // 272B rows: 16B-aligned, 2-way alias
    __shared__ unsigned short h1s[16][136];

    const int t = threadIdx.x;
    const int wv = t >> 6, lane = t & 63;
    const int node0 = blockIdx.x * 16;
    const int g = lane >> 4, c = lane & 15;
    const uint4* x4 = reinterpret_cast<const uint4*>(xb);

    for (int i4 = 0; i4 < 4; ++i4) {
        const int ln = wv * 4 + i4;
        const int node = node0 + ln;
        const int beg = row_ptr[node], end = row_ptr[node + 1];

        float acc[8];
#pragma unroll
        for (int k = 0; k < 8; ++k) acc[k] = 0.f;

        for (int base = beg; base < end; base += 64) {
            const int cnt = min(end - base, 64);
            int s = (base + lane < end) ? esrc[base + lane] : 0;
            for (int i = 0; i < cnt; i += 16) {
                int pp[4]; uint4 vv[4];
#pragma unroll
                for (int j = 0; j < 4; ++j) {
                    pp[j] = i + j * 4 + g;
                    int sj = __shfl(s, pp[j]);
                    vv[j] = x4[(size_t)sj * 16 + c];
                }
#pragma unroll
                for (int j = 0; j < 4; ++j)
                    if (pp[j] < cnt) acc_add(acc, vv[j]);
            }
        }
#pragma unroll
        for (int k = 0; k < 8; ++k) {
            acc[k] += __shfl_xor(acc[k], 16);
            acc[k] += __shfl_xor(acc[k], 32);
        }
        if (g == 0) {
            const float inv = (end > beg) ? 1.0f / (float)(end - beg) : 0.0f;
            uint4 o;
            o.x = (unsigned int)f_to_bf16(acc[0] * inv) | ((unsigned int)f_to_bf16(acc[1] * inv) << 16);
            o.y = (unsigned int)f_to_bf16(acc[2] * inv) | ((unsigned int)f_to_bf16(acc[3] * inv) << 16);
            o.z = (unsigned int)f_to_bf16(acc[4] * inv) | ((unsigned int)f_to_bf16(acc[5] * inv) << 16);
            o.w = (unsigned int)f_to_bf16(acc[6] * inv) | ((unsigned int)f_to_bf16(acc[7] * inv) << 16);
            *reinterpret_cast<uint4*>(&aggs[ln][c * 8]) = o;
        }
    }
    __syncthreads();

    const int c16 = lane & 15, kg = lane >> 4;
    bf16x8 aL[4], aR[4];
#pragma unroll
    for (int kf = 0; kf < 4; ++kf) {
        aL[kf] = *reinterpret_cast<const bf16x8*>(&aggs[c16][kg * 8 + kf * 32]);
        aR[kf] = *reinterpret_cast<const bf16x8*>(xb + (size_t)(node0 + c16) * D + kg * 8 + kf * 32);
    }

#pragma unroll
    for (int jj = 0; jj < 2; ++jj) {
        const int jt = wv + jj * 4;
        f32x4 acc = {0.f, 0.f, 0.f, 0.f};
        const unsigned short* wl = Wb +         (size_t)(jt * 16 + c16) * D + kg * 8;
        const unsigned short* wr = Wb + 16384 + (size_t)(jt * 16 + c16) * D + kg * 8;
#pragma unroll
        for (int kf = 0; kf < 4; ++kf) {
            bf16x8 b = *reinterpret_cast<const bf16x8*>(wl + kf * 32);
            acc = __builtin_amdgcn_mfma_f32_16x16x32_bf16(aL[kf], b, acc, 0, 0, 0);
        }
#pragma unroll
        for (int kf = 0; kf < 4; ++kf) {
            bf16x8 b = *reinterpret_cast<const bf16x8*>(wr + kf * 32);
            acc = __builtin_amdgcn_mfma_f32_16x16x32_bf16(aR[kf], b, acc, 0, 0, 0);
        }
        const float bias = b1[jt * 16 + c16];
#pragma unroll
        for (int i = 0; i < 4; ++i) {
            float v = fmaxf(acc[i] + bias, 0.0f);
            unsigned short us = f_to_bf16(v);
            h1b[(size_t)(node0 + kg * 4 + i) * D + jt * 16 + c16] = us;
            h1s[kg * 4 + i][jt * 16 + c16] = us;
        }
    }
    __syncthreads();

    {   // t2 slice: jt = wv (0..3)
        const int jt = wv;
        bf16x8 a2[4];
#pragma unroll
        for (int kf = 0; kf < 4; ++kf)
            a2[kf] = *reinterpret_cast<const bf16x8*>(&h1s[c16][kg * 8 + kf * 32]);
        f32x4 acc = {0.f, 0.f, 0.f, 0.f};
        const unsigned short* wl = Wb + 32768 + (size_t)(jt * 16 + c16) * D + kg * 8;
#pragma unroll
        for (int kf = 0; kf < 4; ++kf) {
            bf16x8 b = *reinterpret_cast<const bf16x8*>(wl + kf * 32);
            acc = __builtin_amdgcn_mfma_f32_16x16x32_bf16(a2[kf], b, acc, 0, 0, 0);
        }
#pragma unroll
        for (int i = 0; i < 4; ++i)
            t2b[(size_t)(node0 + kg * 4 + i) * D_OUT + jt * 16 + c16] = f_to_bf16(acc[i]);
    }
}

// ---------------------------------------------------------------------------
// Fused gather(t2, 128B rows) + layer2 right GEMM + log_softmax.  [validated]
// ---------------------------------------------------------------------------
__global__ __launch_bounds__(256) void gather_layer2_kernel(
    const unsigned short* __restrict__ t2b,
    const unsigned short* __restrict__ h1b,
    const int* __restrict__ row_ptr, const int* __restrict__ esrc,
    const unsigned short* __restrict__ Wb,   // W2r@40960
    const float* __restrict__ b2, float* __restrict__ out)
{
    __shared__ unsigned short agg2s[16][72];   // 144B rows
    __shared__ float zs[16][68];               // 272B rows

    const int t = threadIdx.x;
    const int wv = t >> 6, lane = t & 63;
    const int node0 = blockIdx.x * 16;
    const int g = lane >> 3, c = lane & 7;     // 8 row slots x 8 chunks
    const uint4* t4 = reinterpret_cast<const uint4*>(t2b);

    for (int i4 = 0; i4 < 4; ++i4) {
        const int ln = wv * 4 + i4;
        const int node = node0 + ln;
        const int beg = row_ptr[node], end = row_ptr[node + 1];

        float acc[8];
#pragma unroll
        for (int k = 0; k < 8; ++k) acc[k] = 0.f;

        for (int base = beg; base < end; base += 64) {
            const int cnt = min(end - base, 64);
            int s = (base + lane < end) ? esrc[base + lane] : 0;
            for (int i = 0; i < cnt; i += 16) {
                int pp[2]; uint4 vv[2];
#pragma unroll
                for (int j = 0; j < 2; ++j) {
                    pp[j] = i + j * 8 + g;
                    int sj = __shfl(s, pp[j]);
                    vv[j] = t4[(size_t)sj * 8 + c];
                }
#pragma unroll
                for (int j = 0; j < 2; ++j)
                    if (pp[j] < cnt) acc_add(acc, vv[j]);
            }
        }
#pragma unroll
        for (int k = 0; k < 8; ++k) {
            acc[k] += __shfl_xor(acc[k], 8);
            acc[k] += __shfl_xor(acc[k], 16);
            acc[k] += __shfl_xor(acc[k], 32);
        }
        if (g == 0) {
            const float inv = (end > beg) ? 1.0f / (float)(end - beg) : 0.0f;
            uint4 o;
            o.x = (unsigned int)f_to_bf16(acc[0] * inv) | ((unsigned int)f_to_bf16(acc[1] * inv) << 16);
            o.y = (unsigned int)f_to_bf16(acc[2] * inv) | ((unsigned int)f_to_bf16(acc[3] * inv) << 16);
            o.z = (unsigned int)f_to_bf16(acc[4] * inv) | ((unsigned int)f_to_bf16(acc[5] * inv) << 16);
            o.w = (unsigned int)f_to_bf16(acc[6] * inv) | ((unsigned int)f_to_bf16(acc[7] * inv) << 16);
            *reinterpret_cast<uint4*>(&agg2s[ln][c * 8]) = o;
        }
    }
    __syncthreads();

    {   // right GEMM slice jt = wv; z staged to LDS
        const int c16 = lane & 15, kg = lane >> 4;
        const int jt = wv;
        bf16x8 a[4];
#pragma unroll
        for (int kf = 0; kf < 4; ++kf)
            a[kf] = *reinterpret_cast<const bf16x8*>(h1b + (size_t)(node0 + c16) * D + kg * 8 + kf * 32);
        f32x4 acc = {0.f, 0.f, 0.f, 0.f};
        const unsigned short* wr = Wb + 40960 + (size_t)(jt * 16 + c16) * D + kg * 8;
#pragma unroll
        for (int kf = 0; kf < 4; ++kf) {
            bf16x8 b = *reinterpret_cast<const bf16x8*>(wr + kf * 32);
            acc = __builtin_amdgcn_mfma_f32_16x16x32_bf16(a[kf], b, acc, 0, 0, 0);
        }
        const float bias = b2[jt * 16 + c16];
#pragma unroll
        for (int i = 0; i < 4; ++i) {
            const int row = kg * 4 + i;
            float left = bf16f(agg2s[row][jt * 16 + c16]);
            zs[row][jt * 16 + c16] = left + acc[i] + bias;
        }
    }
    __syncthreads();

    // softmax: wave wv handles 4 rows; 64-lane reduce
    for (int i4 = 0; i4 < 4; ++i4) {
        const int ln = wv * 4 + i4;
        float z = zs[ln][lane];
        float m = z;
#pragma unroll
        for (int off = 1; off < 64; off <<= 1)
            m = fmaxf(m, __shfl_xor(m, off));
        float e = expf(z - m);
        float s = e;
#pragma unroll
        for (int off = 1; off < 64; off <<= 1)
            s += __shfl_xor(s, off);
        out[(size_t)(node0 + ln) * D_OUT + lane] = z - m - logf(s);
    }
}

// ---------------------------------------------------------------------------
extern "C" void kernel_launch(void* const* d_in, const int* in_sizes, int n_in,
                              void* d_out, int out_size, void* d_ws, size_t ws_size,
                              hipStream_t stream)
{
    const float* x   = (const float*)d_in[0];
    const int*   ei  = (const int*)d_in[1];
    const float* W1l = (const float*)d_in[2];
    const float* b1  = (const float*)d_in[3];
    const float* W1r = (const float*)d_in[4];
    const float* W2l = (const float*)d_in[5];
    const float* b2  = (const float*)d_in[6];
    const float* W2r = (const float*)d_in[7];
    float* out = (float*)d_out;

    const int E = in_sizes[1] / 2;
    const int* src = ei;
    const int* dst = ei + E;

    // ---- workspace layout (256B-aligned chunks) ----
    char* base = (char*)d_ws;
    size_t off = 0;
    auto take = [&](size_t bytes) { char* p = base + off; off += (bytes + 255) & ~(size_t)255; return p; };

    unsigned short* xb  = (unsigned short*)take((size_t)N_NODES * D * 2);
    unsigned short* h1b = (unsigned short*)take((size_t)N_NODES * D * 2);
    unsigned short* t2b = (unsigned short*)take((size_t)N_NODES * D_OUT * 2);
    unsigned short* Wb  = (unsigned short*)take((size_t)49152 * 2);
    int* degcur  = (int*)take((size_t)2 * N_NODES * 4);   // deg | cursor
    int* deg     = degcur;
    int* cursor  = degcur + N_NODES;
    int* row_ptr = (int*)take(((size_t)N_NODES + 1) * 4);
    int* part    = (int*)take((size_t)N_NODES * 4);
    int* bsum    = (int*)take((size_t)64 * 4);
    int* esrc    = (int*)take((size_t)E * 4);

    const int EB = (E + 255) / 256;
    const int SB = (N_NODES + 1023) / 1024;       // 49 scan blocks
    const int XB = (N_NODES * D / 8 + 255) / 256; // 3125 conv_x blocks
    const int MB = N_NODES / 16;                  // 3125 tile blocks, exact

    zero_kernel<<<(2 * N_NODES / 4 + 255) / 256, 256, 0, stream>>>(degcur, 2 * N_NODES / 4);
    prep_kernel<<<XB + 24 + EB, 256, 0, stream>>>(x, xb, W1l, W1r, W2l, W2r, Wb, dst, deg, XB, E);
    scan1_kernel<<<SB, 256, 0, stream>>>(deg, part, bsum, N_NODES);
    scan2_kernel<<<1, 64, 0, stream>>>(bsum, row_ptr, SB, N_NODES);
    scan3_kernel<<<SB, 256, 0, stream>>>(part, bsum, row_ptr, N_NODES);
    fill_kernel<<<EB, 256, 0, stream>>>(src, dst, row_ptr, cursor, esrc, E);

    // fused gather + layer kernels (no agg round-trips)
    gather_layer1_kernel<<<MB, 256, 0, stream>>>(xb, row_ptr, esrc, Wb, b1, h1b, t2b);
    gather_layer2_kernel<<<MB, 256, 0, stream>>>(t2b, h1b, row_ptr, esrc, Wb, b2, out);
}